// Round 18
// baseline (913.107 us; speedup 1.0000x reference)
//
#include <hip/hip_runtime.h>
#include <stdint.h>

// W4A16 dequant-GEMM for MI355X (gfx950) — register-lookahead pipelined round.
// Dtypes (fp16 ref normalized by harness): X f32[8192][4096], W int32[11008][2048]
// (one byte = 2 int4 per element), S f32[11008][32], Y f32[8192][11008].
//
// R17 post-mortem: FETCH halved (1.5->0.63 GB) but time flat -> NOT memory-bound.
// Root cause of the ~50% MfmaUtil plateau (R3..R17): every phase's MFMAs consume
// ds_reads issued in the SAME phase -> wave stalls on lgkmcnt while the shared
// LDS unit (~2304 cyc/tile/CU) serves all waves, then MFMA (2483 cyc) runs with
// LDS idle; measured 4535 cyc/tile == the serialized sum.
// FIX: one-phase register lookahead. Fragment regs doubled (afA/afB, bA/bB);
// phase p issues the reads whose MFMA consumer is phase p+1:
//   ph0: MFMA(0,0)[afA,bA], read bB<-b1(b);    stage A1(t+1)->b^1
//   ph1: MFMA(0,1)[afA,bB], read afB<-af1(b);  stage A0(t+2)->b; GATE(6)
//   ph2: MFMA(1,0)[afB,bA], read afA<-af0(b^1);stage B0(t+2)->b
//   ph3: MFMA(1,1)[afB,bB], read bA<-b0(b^1);  stage B1(t+2)->b; GATE(6)
// Reads are balanced 4/8/8/4 per phase (each < the 620-cyc MFMA window) and no
// MFMA cluster waits on lgkm. Gates (vmcnt counts audited per-read, m135
// oldest-first semantics): A0(t+1) needs <=8 at ph1-gate, B0(t+1) <=6,
// B1(t+1) <=8 at ph3-gate, A1(t+1) <=6 -> vmcnt(6) at both. gate->barrier->read
// discipline kept (R9). L2-chunked 8x4 block map kept (R17, FETCH 2.4x lower).
// Fallback (ws too small): fused single-buffer kernel (round-3-verified algebra).

namespace {

typedef unsigned int u32;
typedef unsigned short u16;
typedef __attribute__((ext_vector_type(8))) short bf16x8;   // 8 bf16 = 4 VGPR
typedef __attribute__((ext_vector_type(4))) float f32x4;
typedef __attribute__((ext_vector_type(4))) u32 u32x4;

constexpr int Mt = 8192;
constexpr int Nt = 11008;
constexpr int Kt = 4096;
constexpr int KP = Kt / 2;     // int32 per W row
constexpr int NG = 32;         // scale groups
constexpr int BM = 256;
constexpr int BN = 256;
constexpr int BK = 64;
constexpr int THREADS = 512;
constexpr int GRID = (Mt / BM) * (Nt / BN);   // 32*43 = 1376 (div by 8)
constexpr int NKT = Kt / BK;                  // 64 K-tiles
constexpr int NB_CNT = Nt / BN;               // 43

__device__ __forceinline__ u16 f2bf(float f) {   // RNE f32 -> bf16 bits
  u32 u = __float_as_uint(f);
  return (u16)((u + 0x7FFFu + ((u >> 16) & 1u)) >> 16);
}
__device__ __forceinline__ u32 pk2bf(float a, float b) {
  return (u32)f2bf(a) | ((u32)f2bf(b) << 16);
}
__device__ __forceinline__ u32 dqpair(u32 b, float s, float c) {
  float f0 = (float)(b & 15u);
  float f1 = (float)((b >> 4) & 15u);
  return pk2bf(fmaf(f0, s, c), fmaf(f1, s, c));
}
__device__ __forceinline__ void async16(const void* g, void* l) {
  __builtin_amdgcn_global_load_lds(
      (const __attribute__((address_space(1))) u32*)g,
      (__attribute__((address_space(3))) u32*)l, 16, 0, 0);
}

// ---- one-shot converters (HBM-bound, ~60 us total) ----
__global__ __launch_bounds__(256) void cvt_x(const float* __restrict__ X,
                                             u32* __restrict__ O) {
  const int total = Mt * Kt / 4;
  for (int j = blockIdx.x * 256 + threadIdx.x; j < total;
       j += (int)(gridDim.x * 256)) {
    float4 v = ((const float4*)X)[j];
    ((uint2*)O)[j] = make_uint2(pk2bf(v.x, v.y), pk2bf(v.z, v.w));
  }
}

__global__ __launch_bounds__(256) void cvt_w(const int* __restrict__ W,
                                             const float* __restrict__ S,
                                             u32* __restrict__ O) {
  const int total = Nt * KP / 4;
  for (int j = blockIdx.x * 256 + threadIdx.x; j < total;
       j += (int)(gridDim.x * 256)) {
    int4 v = ((const int4*)W)[j];
    int vv[4] = {v.x, v.y, v.z, v.w};
    const int j0 = j * 4;            // flat int32 index = row*2048 + jj
    const int row = j0 >> 11;
    const int jj = j0 & 2047;
    const float* sr = S + (size_t)row * NG;
    u32x4 o;
    #pragma unroll
    for (int e = 0; e < 4; ++e) {
      float s = sr[(jj + e) >> 6];   // group = (2*jj)/128 = jj/64
      o[e] = dqpair((u32)vv[e], s, -8.f * s);
    }
    ((u32x4*)O)[j] = o;              // u32 idx jj holds k=2jj (lo), 2jj+1 (hi)
  }
}

// ---- main GEMM: 256x256, BK=64, register-lookahead 4-phase schedule ----
__global__ __launch_bounds__(THREADS, 2) void gemmrl(
    const u16* __restrict__ Xb, const u16* __restrict__ Wb,
    float* __restrict__ Y) {
  // A: [buf][half g] 2x2x16KB at 0..64K; B: same at 64K..128K.
  __shared__ __align__(16) unsigned char smem[131072];

  const int tid  = (int)threadIdx.x;
  const int lane = tid & 63;
  const int wid  = tid >> 6;   // 0..7
  const int wm   = wid >> 2;   // 0..1  (M dir, 128 rows/wave)
  const int wn   = wid & 3;    // 0..3  (N dir, 64 cols/wave)

  // XCD-striped + L2-chunked block map (R17): each XCD's 32 co-resident blocks
  // form an 8mb x 4nb rectangle (384 KB distinct/K-step, L2-resident).
  const int bid = (int)blockIdx.x;
  const int wg  = (bid & 7) * (GRID / 8) + (bid >> 3);
  const int band = wg / 344;               // 8-mb-row band (344 blocks each)
  const int r    = wg - band * 344;
  int mb, nb;
  if (r < 320) {                           // 10 full 8x4 rectangles
    const int qn = r >> 5;
    const int w  = r & 31;
    mb = band * 8 + (w >> 2);
    nb = qn * 4 + (w & 3);
  } else {                                 // last rect: 8x3 (nb 40..42)
    const int r2 = r - 320;
    const int q3 = r2 / 3;
    mb = band * 8 + q3;
    nb = 40 + (r2 - q3 * 3);
  }
  const int m0  = mb * BM;
  const int n0  = nb * BN;

  // ---- staging: half-tile = 16KB = 128 rows x 128B; per thread 2x16B.
  // rows of 128B = 8 x 16B slots; physical slot = logical ^ (row&7); source
  // pre-swizzled so LDS dest is linear (dest = half_base + issue*8192 + tid*16).
  const int srow = tid >> 3;                       // 0..63
  const int sswz = (tid & 7) ^ (srow & 7);         // logical source slot
  const u16* aRow = Xb + (size_t)(m0 + srow) * Kt + sswz * 8;
  const u16* bRow = Wb + (size_t)(n0 + (srow >> 5) * 64 + (srow & 31)) * Kt + sswz * 8;
  const int ldst = tid * 16;

  // ---- fragment-read constants ----
  const int frow = lane & 15;
  const int fk   = lane >> 4;                 // 0..3
  const int s0o  = ((fk ^ (lane & 7)) << 4);        // kk=0 slot byte
  const int s1o  = (((4 + fk) ^ (lane & 7)) << 4);  // kk=1 slot byte
  const int aRdC = (wm * 64 + frow) * 128;
  const int bRdC = (wn * 32 + frow) * 128;

  f32x4 acc[8][4];
  #pragma unroll
  for (int i = 0; i < 8; ++i)
    #pragma unroll
    for (int j = 0; j < 4; ++j) acc[i][j] = f32x4{0.f, 0.f, 0.f, 0.f};

  #define GATE(n) asm volatile("s_waitcnt vmcnt(" #n ")" ::: "memory")
  #define BARR()  asm volatile("s_barrier" ::: "memory")

  #define STAGE_A(g, buf, kt)                                                  \
    do {                                                                       \
      unsigned char* d_ = smem + (buf) * 32768 + (g) * 16384 + ldst;           \
      const u16* s_ = aRow + (size_t)((g) * 64) * Kt + (kt) * 64;              \
      async16(s_, d_);                                                         \
      async16(s_ + (size_t)128 * Kt, d_ + 8192);                               \
    } while (0)
  #define STAGE_B(p, buf, kt)                                                  \
    do {                                                                       \
      unsigned char* d_ = smem + 65536 + (buf) * 32768 + (p) * 16384 + ldst;   \
      const u16* s_ = bRow + (size_t)((p) * 32) * Kt + (kt) * 64;              \
      async16(s_, d_);                                                         \
      async16(s_ + (size_t)128 * Kt, d_ + 8192);                               \
    } while (0)

  #define LD_A(dst, g, buf)                                                    \
    do {                                                                       \
      const unsigned char* b_ = smem + (buf) * 32768 + (g) * 16384 + aRdC;     \
      _Pragma("unroll")                                                        \
      for (int q_ = 0; q_ < 4; ++q_) {                                         \
        dst[q_][0] = *(const bf16x8*)(b_ + q_ * 2048 + s0o);                   \
        dst[q_][1] = *(const bf16x8*)(b_ + q_ * 2048 + s1o);                   \
      }                                                                        \
    } while (0)
  #define LD_B(dst, p, buf)                                                    \
    do {                                                                       \
      const unsigned char* b_ =                                                \
          smem + 65536 + (buf) * 32768 + (p) * 16384 + bRdC;                   \
      _Pragma("unroll")                                                        \
      for (int q_ = 0; q_ < 2; ++q_) {                                         \
        dst[q_][0] = *(const bf16x8*)(b_ + q_ * 2048 + s0o);                   \
        dst[q_][1] = *(const bf16x8*)(b_ + q_ * 2048 + s1o);                   \
      }                                                                        \
    } while (0)

  // Pure MFMA cluster (no barriers, no lgkm dependence on this phase's reads),
  // kk OUTERMOST (dep distance 8, R15).
  #define MMQ(FG, FNP, A_, B_)                                                 \
    do {                                                                       \
      __builtin_amdgcn_s_setprio(1);                                           \
      _Pragma("unroll")                                                        \
      for (int kk_ = 0; kk_ < 2; ++kk_)                                        \
        _Pragma("unroll")                                                      \
        for (int fm_ = 0; fm_ < 4; ++fm_)                                      \
          _Pragma("unroll")                                                    \
          for (int fn_ = 0; fn_ < 2; ++fn_)                                    \
            acc[(FG) * 4 + fm_][(FNP) * 2 + fn_] =                             \
                __builtin_amdgcn_mfma_f32_16x16x32_bf16(                       \
                    A_[fm_][kk_], B_[fn_][kk_],                                \
                    acc[(FG) * 4 + fm_][(FNP) * 2 + fn_], 0, 0, 0);            \
      __builtin_amdgcn_s_setprio(0);                                           \
    } while (0)

  // Optional gate before a closing barrier (literal-folded).
  #define OPTGATE(G)                                                           \
    do {                                                                       \
      if ((G) == 6) { asm volatile("s_waitcnt vmcnt(6)" ::: "memory"); }       \
      else if ((G) == 0) { asm volatile("s_waitcnt vmcnt(0)" ::: "memory"); }  \
    } while (0)

  // One K-tile with register lookahead. S1..S4 enable the 4 stages; G1/G2 are
  // the ph1-end / ph3-end gates (6 steady, 0 at drain, -1 none).
  #define TILE(BUF, T, S1, S2, S3, S4, G1, G2)                                 \
    do {                                                                       \
      /* ph0: MFMA(0,0)[afA,bA]; read bB<-b1(b); stage A1(T+1) */              \
      LD_B(bB, 1, BUF);                                                        \
      if (S1) STAGE_A(1, (BUF) ^ 1, (T) + 1);                                  \
      BARR();                                                                  \
      MMQ(0, 0, afA, bA);                                                      \
      BARR();                                                                  \
      /* ph1: MFMA(0,1)[afA,bB]; read afB<-af1(b); stage A0(T+2); gate */      \
      LD_A(afB, 1, BUF);                                                       \
      if (S2) STAGE_A(0, BUF, (T) + 2);                                        \
      BARR();                                                                  \
      MMQ(0, 1, afA, bB);                                                      \
      OPTGATE(G1);                                                             \
      BARR();                                                                  \
      /* ph2: MFMA(1,0)[afB,bA]; read afA<-af0(b^1); stage B0(T+2) */          \
      LD_A(afA, 0, (BUF) ^ 1);                                                 \
      if (S3) STAGE_B(0, BUF, (T) + 2);                                        \
      BARR();                                                                  \
      MMQ(1, 0, afB, bA);                                                      \
      BARR();                                                                  \
      /* ph3: MFMA(1,1)[afB,bB]; read bA<-b0(b^1); stage B1(T+2); gate */      \
      LD_B(bA, 0, (BUF) ^ 1);                                                  \
      if (S4) STAGE_B(1, BUF, (T) + 2);                                        \
      BARR();                                                                  \
      MMQ(1, 1, afB, bB);                                                      \
      OPTGATE(G2);                                                             \
      BARR();                                                                  \
    } while (0)

  bf16x8 afA[4][2], afB[4][2], bA[2][2], bB[2][2];

  // Prologue: 7 half-tiles (14 loads): tile0 full set + tile1 minus A1.
  STAGE_A(0, 0, 0);   // A0(0)
  STAGE_B(0, 0, 0);   // B0(0)
  STAGE_B(1, 0, 0);   // B1(0)
  STAGE_A(1, 0, 0);   // A1(0)
  STAGE_A(0, 1, 1);   // A0(1)
  STAGE_B(0, 1, 1);   // B0(1)
  STAGE_B(1, 1, 1);   // B1(1)
  GATE(6);            // tile 0 fully landed (newest 6 = A0/B0/B1 of tile 1)
  BARR();
  // Pre-read the first phase's operands.
  LD_A(afA, 0, 0);
  LD_B(bA, 0, 0);

  // Steady loop: tiles 0..61 as 31 x (2 K-tiles), literal buffer indices.
  #pragma unroll 1
  for (int t0 = 0; t0 < NKT - 2; t0 += 2) {
    TILE(0, t0,     1, 1, 1, 1, 6, 6);
    TILE(1, t0 + 1, 1, 1, 1, 1, 6, 6);
  }
  // Tile 62 (buf 0): only A1(63) stage; gates: ph1 vmcnt(6) covers A0(63)
  // (6 newer loads) & B0(63) (4 newer); ph3 vmcnt(0) covers t63's B1/A1 reads.
  TILE(0, 62, 1, 0, 0, 0, 6, 0);
  // Tile 63 (buf 1): no stages, everything landed; straight-line.
  {
    LD_B(bB, 1, 1);
    LD_A(afB, 1, 1);
    MMQ(0, 0, afA, bA);
    MMQ(0, 1, afA, bB);
    MMQ(1, 0, afB, bA);
    MMQ(1, 1, afB, bB);
  }

  #undef GATE
  #undef BARR
  #undef STAGE_A
  #undef STAGE_B
  #undef LD_A
  #undef LD_B
  #undef MMQ
  #undef OPTGATE
  #undef TILE

  // Epilogue: C/D mapping col = lane&15, row = (lane>>4)*4 + reg (m89/m91).
  #pragma unroll
  for (int fm = 0; fm < 8; ++fm) {
    #pragma unroll
    for (int r2 = 0; r2 < 4; ++r2) {
      const size_t mrow = (size_t)(m0 + wm * 128 + fm * 16 + fk * 4 + r2) * Nt;
      #pragma unroll
      for (int fn = 0; fn < 4; ++fn) {
        Y[mrow + (size_t)(n0 + wn * 64 + fn * 16 + frow)] = acc[fm][fn][r2];
      }
    }
  }
}

// ---- fallback: fused single-buffer kernel (round-3 verified algebra) ----
__global__ __launch_bounds__(512) void gemm_fused(
    const float* __restrict__ Xf, const int* __restrict__ W,
    const float* __restrict__ S, float* __restrict__ Y) {
  constexpr int FBN = 128;
  constexpr int FNB = Nt / FBN;   // 86
  constexpr int FBK = 64;
  constexpr int FNKT = Kt / FBK;
  __shared__ __align__(16) unsigned char Alds[BM * FBK * 2];
  __shared__ __align__(16) unsigned char Blds[FBN * FBK * 2];

  const int tid = (int)threadIdx.x;
  const int lane = tid & 63;
  const int wid = tid >> 6;
  const int wm = wid >> 1;
  const int wn = wid & 1;

  const int bid = (int)blockIdx.x;
  const int fgrid = (Mt / BM) * FNB;
  const int wg = (bid & 7) * (fgrid / 8) + (bid >> 3);
  const int mb = wg / FNB;
  const int nb = wg - mb * FNB;
  const int m0 = mb * BM;
  const int n0 = nb * FBN;

  const int frow = lane & 15;
  const int fk = lane >> 4;
  const int fswz = (lane & 7) << 4;
  const unsigned char* aRd = Alds + (wm * 64 + frow) * 128;
  const unsigned char* bRd = Blds + (wn * 64 + frow) * 128;

  f32x4 acc[4][4];
  #pragma unroll
  for (int i = 0; i < 4; ++i)
    #pragma unroll
    for (int j = 0; j < 4; ++j) acc[i][j] = f32x4{0.f, 0.f, 0.f, 0.f};

  const int arow = tid >> 3, acol = tid & 7;
  const float* fA = Xf + (size_t)(m0 + arow) * Kt + acol * 8;
  unsigned char* fAD = Alds + arow * 128 + ((acol ^ (arow & 7)) << 4);
  const int nloc = tid >> 3, c4 = tid & 7;
  const int* fB0 = W + (size_t)(n0 + nloc) * KP + c4 * 4;
  const int* fB1 = fB0 + (size_t)64 * KP;
  const float* sp0 = S + (size_t)(n0 + nloc) * NG;
  const float* sp1 = sp0 + (size_t)64 * NG;
  unsigned char* fBD0 = Blds + nloc * 128 + ((c4 ^ (nloc & 7)) << 4);
  unsigned char* fBD1 = fBD0 + 64 * 128;

  #pragma unroll 1
  for (int kt = 0; kt < FNKT; ++kt) {
    const int k0 = kt * FBK;
    #pragma unroll
    for (int p = 0; p < 4; ++p) {
      float4 x0 = *(const float4*)(fA + (size_t)p * 64 * Kt + k0);
      float4 x1 = *(const float4*)(fA + (size_t)p * 64 * Kt + k0 + 4);
      u32x4 q;
      q[0] = pk2bf(x0.x, x0.y); q[1] = pk2bf(x0.z, x0.w);
      q[2] = pk2bf(x1.x, x1.y); q[3] = pk2bf(x1.z, x1.w);
      *(u32x4*)(fAD + p * 64 * 128) = q;
    }
    const int g = k0 >> 7;
    const float s0 = sp0[g], s1 = sp1[g];
    const float c0 = -8.f * s0, c1 = -8.f * s1;
    const int4 w0 = *(const int4*)(fB0 + (k0 >> 1));
    const int4 w1 = *(const int4*)(fB1 + (k0 >> 1));
    u32x4 q0, q1;
    q0[0] = dqpair((u32)w0.x, s0, c0); q0[1] = dqpair((u32)w0.y, s0, c0);
    q0[2] = dqpair((u32)w0.z, s0, c0); q0[3] = dqpair((u32)w0.w, s0, c0);
    q1[0] = dqpair((u32)w1.x, s1, c1); q1[1] = dqpair((u32)w1.y, s1, c1);
    q1[2] = dqpair((u32)w1.z, s1, c1); q1[3] = dqpair((u32)w1.w, s1, c1);
    *(u32x4*)fBD0 = q0;
    *(u32x4*)fBD1 = q1;

    __syncthreads();

    #pragma unroll
    for (int kk = 0; kk < 2; ++kk) {
      const int koff = (kk * 64 + fk * 16) ^ fswz;
      bf16x8 af[4], bfr[4];
      #pragma unroll
      for (int fm = 0; fm < 4; ++fm)
        af[fm] = *(const bf16x8*)(aRd + fm * 16 * 128 + koff);
      #pragma unroll
      for (int fn = 0; fn < 4; ++fn)
        bfr[fn] = *(const bf16x8*)(bRd + fn * 16 * 128 + koff);
      #pragma unroll
      for (int fm = 0; fm < 4; ++fm)
        #pragma unroll
        for (int fn = 0; fn < 4; ++fn)
          acc[fm][fn] = __builtin_amdgcn_mfma_f32_16x16x32_bf16(
              af[fm], bfr[fn], acc[fm][fn], 0, 0, 0);
    }
    __syncthreads();
  }

  #pragma unroll
  for (int fm = 0; fm < 4; ++fm) {
    #pragma unroll
    for (int r = 0; r < 4; ++r) {
      const size_t mrow = (size_t)(m0 + wm * 64 + fm * 16 + fk * 4 + r) * Nt;
      #pragma unroll
      for (int fn = 0; fn < 4; ++fn)
        Y[mrow + (size_t)(n0 + wn * 64 + fn * 16 + frow)] = acc[fm][fn][r];
    }
  }
}

}  // namespace

extern "C" void kernel_launch(void* const* d_in, const int* in_sizes, int n_in,
                              void* d_out, int out_size, void* d_ws, size_t ws_size,
                              hipStream_t stream) {
  (void)in_sizes; (void)n_in; (void)out_size;
  const float* X = (const float*)d_in[0];
  const int* W   = (const int*)d_in[1];
  const float* S = (const float*)d_in[2];
  float* Y       = (float*)d_out;

  const size_t xbytes = (size_t)Mt * Kt * 2;   // 64 MiB
  const size_t wbytes = (size_t)Nt * Kt * 2;   // 86 MiB

  if (ws_size >= xbytes + wbytes) {
    u16* Xb = (u16*)d_ws;
    u16* Wb = (u16*)((char*)d_ws + xbytes);
    cvt_x<<<dim3(2048), dim3(256), 0, stream>>>(X, (u32*)Xb);
    cvt_w<<<dim3(2048), dim3(256), 0, stream>>>(W, S, (u32*)Wb);
    gemmrl<<<dim3(GRID), dim3(THREADS), 0, stream>>>(Xb, Wb, Y);
  } else {
    gemm_fused<<<dim3((Mt / BM) * (Nt / 128)), dim3(512), 0, stream>>>(X, W, S, Y);
  }
}

// Round 19
// 894.915 us; speedup vs baseline: 1.0203x; 1.0203x over previous
//
#include <hip/hip_runtime.h>
#include <stdint.h>

// W4A16 dequant-GEMM for MI355X (gfx950) — B-direct-to-reg (k-chunk-major W).
// Dtypes (fp16 ref normalized by harness): X f32[8192][4096], W int32[11008][2048]
// (one byte = 2 int4 per element), S f32[11008][32], Y f32[8192][11008].
//
// R18 post-mortem / cross-round regression: cycles per ds_read_b128 is ~20-24
// across ALL structures (R6: 2590cyc/256reads, R11..R17: ~4535/192) while MFMA
// is only ~620 cyc/SIMD/tile -> the kernel is LDS-read-service bound, not
// MFMA- or schedule-bound. Only traffic reduction helps.
// THIS ROUND: B never touches LDS. cvt_w emits W transposed k-chunk-major
// (W2[k/8][n] = 16B chunk), so a wave's B-fragment global load is coalesced
// (16 lanes x 16B contiguous per fk segment). B prefetched one K-tile ahead
// into parity register sets (bA/bB). A unchanged (global_load_lds + verified
// XOR swizzle), LDS 64 KiB. LDS reads/wave/tile: 24 -> 16.
// One GATE(0)+barrier per K-tile (all VMEM issued a full tile earlier ->
// drain free; gate->barrier->read discipline kept). L2-chunked 8x4 map kept.
// Fallback (ws too small): fused single-buffer kernel (round-3-verified algebra).

namespace {

typedef unsigned int u32;
typedef unsigned short u16;
typedef __attribute__((ext_vector_type(8))) short bf16x8;   // 8 bf16 = 4 VGPR
typedef __attribute__((ext_vector_type(4))) float f32x4;
typedef __attribute__((ext_vector_type(4))) u32 u32x4;

constexpr int Mt = 8192;
constexpr int Nt = 11008;
constexpr int Kt = 4096;
constexpr int KP = Kt / 2;     // int32 per W row
constexpr int NG = 32;         // scale groups
constexpr int BM = 256;
constexpr int BN = 256;
constexpr int BK = 64;
constexpr int THREADS = 512;
constexpr int GRID = (Mt / BM) * (Nt / BN);   // 32*43 = 1376 (div by 8)
constexpr int NKT = Kt / BK;                  // 64 K-tiles
constexpr int NB_CNT = Nt / BN;               // 43

__device__ __forceinline__ u16 f2bf(float f) {   // RNE f32 -> bf16 bits
  u32 u = __float_as_uint(f);
  return (u16)((u + 0x7FFFu + ((u >> 16) & 1u)) >> 16);
}
__device__ __forceinline__ u32 pk2bf(float a, float b) {
  return (u32)f2bf(a) | ((u32)f2bf(b) << 16);
}
__device__ __forceinline__ u32 dqpair(u32 b, float s, float c) {
  float f0 = (float)(b & 15u);
  float f1 = (float)((b >> 4) & 15u);
  return pk2bf(fmaf(f0, s, c), fmaf(f1, s, c));
}
__device__ __forceinline__ void async16(const void* g, void* l) {
  __builtin_amdgcn_global_load_lds(
      (const __attribute__((address_space(1))) u32*)g,
      (__attribute__((address_space(3))) u32*)l, 16, 0, 0);
}

// ---- one-shot converters ----
__global__ __launch_bounds__(256) void cvt_x(const float* __restrict__ X,
                                             u32* __restrict__ O) {
  const int total = Mt * Kt / 4;
  for (int j = blockIdx.x * 256 + threadIdx.x; j < total;
       j += (int)(gridDim.x * 256)) {
    float4 v = ((const float4*)X)[j];
    ((uint2*)O)[j] = make_uint2(pk2bf(v.x, v.y), pk2bf(v.z, v.w));
  }
}

// W -> bf16, k-chunk-major: O2[c][n] (c = k/8, 16B per entry).
// Thread j handles row n = (4j)>>11, int32s jj..jj+3 (jj = (4j)&2047) =
// k 2jj..2jj+7 = chunk c = jj>>2. Reads coalesced; writes 16B scattered
// (stride Nt*16B) — acceptable one-off cost.
__global__ __launch_bounds__(256) void cvt_w(const int* __restrict__ W,
                                             const float* __restrict__ S,
                                             u32* __restrict__ O) {
  const int total = Nt * KP / 4;
  for (int j = blockIdx.x * 256 + threadIdx.x; j < total;
       j += (int)(gridDim.x * 256)) {
    int4 v = ((const int4*)W)[j];
    int vv[4] = {v.x, v.y, v.z, v.w};
    const int j0 = j * 4;
    const int row = j0 >> 11;
    const int jj = j0 & 2047;
    const float* sr = S + (size_t)row * NG;
    u32x4 o;
    #pragma unroll
    for (int e = 0; e < 4; ++e) {
      float s = sr[(jj + e) >> 6];   // group = (2*jj)/128 = jj/64
      o[e] = dqpair((u32)vv[e], s, -8.f * s);
    }
    ((u32x4*)O)[(size_t)(jj >> 2) * Nt + row] = o;
  }
}

// ---- main GEMM: 256x256, BK=64, A via LDS, B direct-to-reg ----
__global__ __launch_bounds__(THREADS, 2) void gemmbd(
    const u16* __restrict__ Xb, const u16* __restrict__ Wb,
    float* __restrict__ Y) {
  // A only: [buf][half g] 2x2x16KB = 64 KiB.
  __shared__ __align__(16) unsigned char smem[65536];

  const int tid  = (int)threadIdx.x;
  const int lane = tid & 63;
  const int wid  = tid >> 6;   // 0..7
  const int wm   = wid >> 2;   // 0..1  (M dir, 128 rows/wave)
  const int wn   = wid & 3;    // 0..3  (N dir, 64 cols/wave)

  // XCD-striped + L2-chunked block map (R17).
  const int bid = (int)blockIdx.x;
  const int wg  = (bid & 7) * (GRID / 8) + (bid >> 3);
  const int band = wg / 344;
  const int r    = wg - band * 344;
  int mb, nb;
  if (r < 320) {
    const int qn = r >> 5;
    const int w  = r & 31;
    mb = band * 8 + (w >> 2);
    nb = qn * 4 + (w & 3);
  } else {
    const int r2 = r - 320;
    const int q3 = r2 / 3;
    mb = band * 8 + q3;
    nb = 40 + (r2 - q3 * 3);
  }
  const int m0  = mb * BM;
  const int n0  = nb * BN;

  // ---- A staging (verified): half-tile = 16KB; per thread 2x16B; physical
  // slot = logical ^ (row&7); source pre-swizzled, LDS dest linear.
  const int srow = tid >> 3;
  const int sswz = (tid & 7) ^ (srow & 7);
  const u16* aRow = Xb + (size_t)(m0 + srow) * Kt + sswz * 8;
  const int ldst = tid * 16;

  // ---- fragment constants ----
  const int frow = lane & 15;
  const int fk   = lane >> 4;                 // 0..3
  const int s0o  = ((fk ^ (lane & 7)) << 4);
  const int s1o  = (((4 + fk) ^ (lane & 7)) << 4);
  const int aRdC = (wm * 64 + frow) * 128;

  // B global base: W2[c][n], c = kt*8 + kk*4 + fk, n = n0 + wn*64 + fn*16 + frow.
  const bf16x8* wBp = (const bf16x8*)Wb;
  const size_t nIdx = (size_t)(n0 + wn * 64 + frow);

  f32x4 acc[8][4];
  #pragma unroll
  for (int i = 0; i < 8; ++i)
    #pragma unroll
    for (int j = 0; j < 4; ++j) acc[i][j] = f32x4{0.f, 0.f, 0.f, 0.f};

  #define GATE0() asm volatile("s_waitcnt vmcnt(0)" ::: "memory")
  #define BARR()  asm volatile("s_barrier" ::: "memory")

  #define STAGE_A(g, buf, kt)                                                  \
    do {                                                                       \
      unsigned char* d_ = smem + (buf) * 32768 + (g) * 16384 + ldst;           \
      const u16* s_ = aRow + (size_t)((g) * 64) * Kt + (kt) * 64;              \
      async16(s_, d_);                                                         \
      async16(s_ + (size_t)128 * Kt, d_ + 8192);                               \
    } while (0)

  #define LD_A(dst, g, buf)                                                    \
    do {                                                                       \
      const unsigned char* b_ = smem + (buf) * 32768 + (g) * 16384 + aRdC;     \
      _Pragma("unroll")                                                        \
      for (int q_ = 0; q_ < 4; ++q_) {                                         \
        dst[q_][0] = *(const bf16x8*)(b_ + q_ * 2048 + s0o);                   \
        dst[q_][1] = *(const bf16x8*)(b_ + q_ * 2048 + s1o);                   \
      }                                                                        \
    } while (0)

  // B fragment set for K-tile KT: 8 coalesced global loads (per-wave).
  #define LOADB(DST, KT)                                                       \
    do {                                                                       \
      _Pragma("unroll")                                                        \
      for (int fn_ = 0; fn_ < 4; ++fn_)                                        \
        _Pragma("unroll")                                                      \
        for (int kk_ = 0; kk_ < 2; ++kk_)                                      \
          DST[fn_][kk_] =                                                      \
              wBp[(size_t)((KT) * 8 + kk_ * 4 + fk) * Nt + nIdx + fn_ * 16];   \
    } while (0)

  // C-quadrant (16 MFMA), kk outermost (dep distance 8).
  #define MMQ(FG, FNP, A_, B_)                                                 \
    do {                                                                       \
      __builtin_amdgcn_s_setprio(1);                                           \
      _Pragma("unroll")                                                        \
      for (int kk_ = 0; kk_ < 2; ++kk_)                                        \
        _Pragma("unroll")                                                      \
        for (int fm_ = 0; fm_ < 4; ++fm_)                                      \
          _Pragma("unroll")                                                    \
          for (int fn_ = 0; fn_ < 2; ++fn_)                                    \
            acc[(FG) * 4 + fm_][(FNP) * 2 + fn_] =                             \
                __builtin_amdgcn_mfma_f32_16x16x32_bf16(                       \
                    A_[fm_][kk_], B_[(FNP) * 2 + fn_][kk_],                    \
                    acc[(FG) * 4 + fm_][(FNP) * 2 + fn_], 0, 0, 0);            \
      __builtin_amdgcn_s_setprio(0);                                           \
    } while (0)

  // One K-tile. Prefetch B(t+1) + stage A(t+1) first (a full tile of latency),
  // then A reads + 4 MFMA quadrants, then the (free) drain + barrier.
  #define TILE(BUF, T, BC, BN_, DOPRE, DOSYNC)                                 \
    do {                                                                       \
      if (DOPRE) {                                                             \
        LOADB(BN_, (T) + 1);                                                   \
        STAGE_A(0, (BUF) ^ 1, (T) + 1);                                        \
        STAGE_A(1, (BUF) ^ 1, (T) + 1);                                        \
      }                                                                        \
      LD_A(af, 0, BUF);                                                        \
      MMQ(0, 0, af, BC);                                                       \
      MMQ(0, 1, af, BC);                                                       \
      LD_A(af, 1, BUF);                                                        \
      MMQ(1, 0, af, BC);                                                       \
      MMQ(1, 1, af, BC);                                                       \
      if (DOSYNC) { GATE0(); BARR(); }                                         \
    } while (0)

  bf16x8 af[4][2];
  bf16x8 bA[4][2], bB[4][2];

  // Prologue: stage A(0) into buf0, load B(0) into bA; drain; barrier.
  STAGE_A(0, 0, 0);
  STAGE_A(1, 0, 0);
  LOADB(bA, 0);
  GATE0();
  BARR();

  // Steady: tiles 0..61 as 31 x (2 K-tiles); parity regs/buffers literal.
  #pragma unroll 1
  for (int t0 = 0; t0 < NKT - 2; t0 += 2) {
    TILE(0, t0,     bA, bB, 1, 1);
    TILE(1, t0 + 1, bB, bA, 1, 1);
  }
  // t = 62 (buf 0, bA current): prefetch tile 63 (B into bB, A into buf1).
  TILE(0, 62, bA, bB, 1, 1);
  // t = 63 (buf 1, bB current): nothing to prefetch; no trailing sync.
  TILE(1, 63, bB, bA, 0, 0);

  #undef GATE0
  #undef BARR
  #undef STAGE_A
  #undef LD_A
  #undef LOADB
  #undef MMQ
  #undef TILE

  // Epilogue: C/D mapping col = lane&15, row = (lane>>4)*4 + reg (m89/m91).
  #pragma unroll
  for (int fm = 0; fm < 8; ++fm) {
    #pragma unroll
    for (int r2 = 0; r2 < 4; ++r2) {
      const size_t mrow = (size_t)(m0 + wm * 128 + fm * 16 + fk * 4 + r2) * Nt;
      #pragma unroll
      for (int fn = 0; fn < 4; ++fn) {
        Y[mrow + (size_t)(n0 + wn * 64 + fn * 16 + frow)] = acc[fm][fn][r2];
      }
    }
  }
}

// ---- fallback: fused single-buffer kernel (round-3 verified algebra) ----
__global__ __launch_bounds__(512) void gemm_fused(
    const float* __restrict__ Xf, const int* __restrict__ W,
    const float* __restrict__ S, float* __restrict__ Y) {
  constexpr int FBN = 128;
  constexpr int FNB = Nt / FBN;   // 86
  constexpr int FBK = 64;
  constexpr int FNKT = Kt / FBK;
  __shared__ __align__(16) unsigned char Alds[BM * FBK * 2];
  __shared__ __align__(16) unsigned char Blds[FBN * FBK * 2];

  const int tid = (int)threadIdx.x;
  const int lane = tid & 63;
  const int wid = tid >> 6;
  const int wm = wid >> 1;
  const int wn = wid & 1;

  const int bid = (int)blockIdx.x;
  const int fgrid = (Mt / BM) * FNB;
  const int wg = (bid & 7) * (fgrid / 8) + (bid >> 3);
  const int mb = wg / FNB;
  const int nb = wg - mb * FNB;
  const int m0 = mb * BM;
  const int n0 = nb * FBN;

  const int frow = lane & 15;
  const int fk = lane >> 4;
  const int fswz = (lane & 7) << 4;
  const unsigned char* aRd = Alds + (wm * 64 + frow) * 128;
  const unsigned char* bRd = Blds + (wn * 64 + frow) * 128;

  f32x4 acc[4][4];
  #pragma unroll
  for (int i = 0; i < 4; ++i)
    #pragma unroll
    for (int j = 0; j < 4; ++j) acc[i][j] = f32x4{0.f, 0.f, 0.f, 0.f};

  const int arow = tid >> 3, acol = tid & 7;
  const float* fA = Xf + (size_t)(m0 + arow) * Kt + acol * 8;
  unsigned char* fAD = Alds + arow * 128 + ((acol ^ (arow & 7)) << 4);
  const int nloc = tid >> 3, c4 = tid & 7;
  const int* fB0 = W + (size_t)(n0 + nloc) * KP + c4 * 4;
  const int* fB1 = fB0 + (size_t)64 * KP;
  const float* sp0 = S + (size_t)(n0 + nloc) * NG;
  const float* sp1 = sp0 + (size_t)64 * NG;
  unsigned char* fBD0 = Blds + nloc * 128 + ((c4 ^ (nloc & 7)) << 4);
  unsigned char* fBD1 = fBD0 + 64 * 128;

  #pragma unroll 1
  for (int kt = 0; kt < FNKT; ++kt) {
    const int k0 = kt * FBK;
    #pragma unroll
    for (int p = 0; p < 4; ++p) {
      float4 x0 = *(const float4*)(fA + (size_t)p * 64 * Kt + k0);
      float4 x1 = *(const float4*)(fA + (size_t)p * 64 * Kt + k0 + 4);
      u32x4 q;
      q[0] = pk2bf(x0.x, x0.y); q[1] = pk2bf(x0.z, x0.w);
      q[2] = pk2bf(x1.x, x1.y); q[3] = pk2bf(x1.z, x1.w);
      *(u32x4*)(fAD + p * 64 * 128) = q;
    }
    const int g = k0 >> 7;
    const float s0 = sp0[g], s1 = sp1[g];
    const float c0 = -8.f * s0, c1 = -8.f * s1;
    const int4 w0 = *(const int4*)(fB0 + (k0 >> 1));
    const int4 w1 = *(const int4*)(fB1 + (k0 >> 1));
    u32x4 q0, q1;
    q0[0] = dqpair((u32)w0.x, s0, c0); q0[1] = dqpair((u32)w0.y, s0, c0);
    q0[2] = dqpair((u32)w0.z, s0, c0); q0[3] = dqpair((u32)w0.w, s0, c0);
    q1[0] = dqpair((u32)w1.x, s1, c1); q1[1] = dqpair((u32)w1.y, s1, c1);
    q1[2] = dqpair((u32)w1.z, s1, c1); q1[3] = dqpair((u32)w1.w, s1, c1);
    *(u32x4*)fBD0 = q0;
    *(u32x4*)fBD1 = q1;

    __syncthreads();

    #pragma unroll
    for (int kk = 0; kk < 2; ++kk) {
      const int koff = (kk * 64 + fk * 16) ^ fswz;
      bf16x8 af[4], bfr[4];
      #pragma unroll
      for (int fm = 0; fm < 4; ++fm)
        af[fm] = *(const bf16x8*)(aRd + fm * 16 * 128 + koff);
      #pragma unroll
      for (int fn = 0; fn < 4; ++fn)
        bfr[fn] = *(const bf16x8*)(bRd + fn * 16 * 128 + koff);
      #pragma unroll
      for (int fm = 0; fm < 4; ++fm)
        #pragma unroll
        for (int fn = 0; fn < 4; ++fn)
          acc[fm][fn] = __builtin_amdgcn_mfma_f32_16x16x32_bf16(
              af[fm], bfr[fn], acc[fm][fn], 0, 0, 0);
    }
    __syncthreads();
  }

  #pragma unroll
  for (int fm = 0; fm < 4; ++fm) {
    #pragma unroll
    for (int r = 0; r < 4; ++r) {
      const size_t mrow = (size_t)(m0 + wm * 64 + fm * 16 + fk * 4 + r) * Nt;
      #pragma unroll
      for (int fn = 0; fn < 4; ++fn)
        Y[mrow + (size_t)(n0 + wn * 64 + fn * 16 + frow)] = acc[fm][fn][r];
    }
  }
}

}  // namespace

extern "C" void kernel_launch(void* const* d_in, const int* in_sizes, int n_in,
                              void* d_out, int out_size, void* d_ws, size_t ws_size,
                              hipStream_t stream) {
  (void)in_sizes; (void)n_in; (void)out_size;
  const float* X = (const float*)d_in[0];
  const int* W   = (const int*)d_in[1];
  const float* S = (const float*)d_in[2];
  float* Y       = (float*)d_out;

  const size_t xbytes = (size_t)Mt * Kt * 2;   // 64 MiB
  const size_t wbytes = (size_t)Nt * Kt * 2;   // 86 MiB

  if (ws_size >= xbytes + wbytes) {
    u16* Xb = (u16*)d_ws;
    u16* Wb = (u16*)((char*)d_ws + xbytes);
    cvt_x<<<dim3(2048), dim3(256), 0, stream>>>(X, (u32*)Xb);
    cvt_w<<<dim3(2048), dim3(256), 0, stream>>>(W, S, (u32*)Wb);
    gemmbd<<<dim3(GRID), dim3(THREADS), 0, stream>>>(Xb, Wb, Y);
  } else {
    gemm_fused<<<dim3((Mt / BM) * (Nt / 128)), dim3(512), 0, stream>>>(X, W, S, Y);
  }
}

// Round 20
// 675.872 us; speedup vs baseline: 1.3510x; 1.3241x over previous
//
#include <hip/hip_runtime.h>
#include <stdint.h>

// W4A16 dequant-GEMM for MI355X (gfx950) — FINAL: R17 (best verified, 676.8us).
// Dtypes (fp16 ref normalized by harness): X f32[8192][4096], W int32[11008][2048]
// (one byte = 2 int4 per element), S f32[11008][32], Y f32[8192][11008].
//
// Fast path: cvt_x (X->bf16) + cvt_w (dequant W->bf16) into d_ws, then bf16 GEMM:
// 256x256 tile, BK=64, 512 thr = 8 waves (2M x 4N), 128x64 out/wave (acc[8][4]),
// LDS 128 KiB = {A,B} x 2buf x 2half x 16KB, 4 phases/K-tile (reads+stage before
// barrier-1, 16 MFMA kk-outer between barriers), GATE(6) before the tile-ending
// barrier (gate->barrier->read), x2 unroll for literal buffer indices,
// L2-chunked 8mb x 4nb block map (FETCH 1.5GB -> 0.63GB).
// Falsification sweep (R3..R19): barrier structure, counted-vmcnt depth, reg
// lookahead, B-direct-to-reg, 32x32 fragments, occupancy variants all null or
// regressions; this configuration is the measured optimum (1133 TF effective).
// Fallback (ws too small): fused single-buffer kernel (round-3-verified algebra).

namespace {

typedef unsigned int u32;
typedef unsigned short u16;
typedef __attribute__((ext_vector_type(8))) short bf16x8;   // 8 bf16 = 4 VGPR
typedef __attribute__((ext_vector_type(4))) float f32x4;
typedef __attribute__((ext_vector_type(4))) u32 u32x4;

constexpr int Mt = 8192;
constexpr int Nt = 11008;
constexpr int Kt = 4096;
constexpr int KP = Kt / 2;     // int32 per W row
constexpr int NG = 32;         // scale groups
constexpr int BM = 256;
constexpr int BN = 256;
constexpr int BK = 64;
constexpr int THREADS = 512;
constexpr int GRID = (Mt / BM) * (Nt / BN);   // 32*43 = 1376 (div by 8)
constexpr int NKT = Kt / BK;                  // 64 K-tiles
constexpr int NB_CNT = Nt / BN;               // 43

__device__ __forceinline__ u16 f2bf(float f) {   // RNE f32 -> bf16 bits
  u32 u = __float_as_uint(f);
  return (u16)((u + 0x7FFFu + ((u >> 16) & 1u)) >> 16);
}
__device__ __forceinline__ u32 pk2bf(float a, float b) {
  return (u32)f2bf(a) | ((u32)f2bf(b) << 16);
}
__device__ __forceinline__ u32 dqpair(u32 b, float s, float c) {
  float f0 = (float)(b & 15u);
  float f1 = (float)((b >> 4) & 15u);
  return pk2bf(fmaf(f0, s, c), fmaf(f1, s, c));
}
__device__ __forceinline__ void async16(const void* g, void* l) {
  __builtin_amdgcn_global_load_lds(
      (const __attribute__((address_space(1))) u32*)g,
      (__attribute__((address_space(3))) u32*)l, 16, 0, 0);
}

// ---- one-shot converters (HBM-bound, ~60 us total) ----
__global__ __launch_bounds__(256) void cvt_x(const float* __restrict__ X,
                                             u32* __restrict__ O) {
  const int total = Mt * Kt / 4;
  for (int j = blockIdx.x * 256 + threadIdx.x; j < total;
       j += (int)(gridDim.x * 256)) {
    float4 v = ((const float4*)X)[j];
    ((uint2*)O)[j] = make_uint2(pk2bf(v.x, v.y), pk2bf(v.z, v.w));
  }
}

__global__ __launch_bounds__(256) void cvt_w(const int* __restrict__ W,
                                             const float* __restrict__ S,
                                             u32* __restrict__ O) {
  const int total = Nt * KP / 4;
  for (int j = blockIdx.x * 256 + threadIdx.x; j < total;
       j += (int)(gridDim.x * 256)) {
    int4 v = ((const int4*)W)[j];
    int vv[4] = {v.x, v.y, v.z, v.w};
    const int j0 = j * 4;            // flat int32 index = row*2048 + jj
    const int row = j0 >> 11;
    const int jj = j0 & 2047;
    const float* sr = S + (size_t)row * NG;
    u32x4 o;
    #pragma unroll
    for (int e = 0; e < 4; ++e) {
      float s = sr[(jj + e) >> 6];   // group = (2*jj)/128 = jj/64
      o[e] = dqpair((u32)vv[e], s, -8.f * s);
    }
    ((u32x4*)O)[j] = o;              // u32 idx jj holds k=2jj (lo), 2jj+1 (hi)
  }
}

// ---- main GEMM: 256x256, BK=64, 4-phase schedule, x2 unroll ----
__global__ __launch_bounds__(THREADS, 2) void gemm8p(
    const u16* __restrict__ Xb, const u16* __restrict__ Wb,
    float* __restrict__ Y) {
  // A: [buf][half g] 2x2x16KB at 0..64K; B: same at 64K..128K.
  __shared__ __align__(16) unsigned char smem[131072];

  const int tid  = (int)threadIdx.x;
  const int lane = tid & 63;
  const int wid  = tid >> 6;   // 0..7
  const int wm   = wid >> 2;   // 0..1  (M dir, 128 rows/wave)
  const int wn   = wid & 3;    // 0..3  (N dir, 64 cols/wave)

  // XCD-striped + L2-chunked block map: wg = per-XCD-contiguous index; then
  // map wg to an 8mb x 4nb rectangle so each XCD's 32 co-resident blocks
  // share 8 A-panels + 4 B-panels (384 KB distinct per K-step, L2-resident).
  const int bid = (int)blockIdx.x;
  const int wg  = (bid & 7) * (GRID / 8) + (bid >> 3);
  const int band = wg / 344;               // 8-mb-row band (344 blocks each)
  const int r    = wg - band * 344;
  int mb, nb;
  if (r < 320) {                           // 10 full 8x4 rectangles
    const int qn = r >> 5;                 // rect column 0..9
    const int w  = r & 31;
    mb = band * 8 + (w >> 2);
    nb = qn * 4 + (w & 3);
  } else {                                 // last rect: 8x3 (nb 40..42)
    const int r2 = r - 320;
    const int q3 = r2 / 3;
    mb = band * 8 + q3;
    nb = 40 + (r2 - q3 * 3);
  }
  const int m0  = mb * BM;
  const int n0  = nb * BN;

  // ---- staging: half-tile = 16KB = 128 rows x 128B; per thread 2x16B.
  // rows of 128B = 8 x 16B slots; physical slot = logical ^ (row&7); source
  // pre-swizzled so LDS dest is linear (dest = half_base + issue*8192 + tid*16).
  const int srow = tid >> 3;                       // 0..63
  const int sswz = (tid & 7) ^ (srow & 7);         // logical source slot
  // A half g, issue i covers global row m0 + i*128 + g*64 + srow.
  const u16* aRow = Xb + (size_t)(m0 + srow) * Kt + sswz * 8;
  // B half p (fnp strips), issue i: row n0 + (i*2 + srow/32)*64 + p*32 + (srow&31).
  const u16* bRow = Wb + (size_t)(n0 + (srow >> 5) * 64 + (srow & 31)) * Kt + sswz * 8;
  const int ldst = tid * 16;

  // ---- fragment-read constants ----
  // af[fm'][kk]: row_local = wm*64 + fm'*16 + frow in half g; byte in row:
  // slot = (kk*4+fk) ^ (row&7), row&7 == lane&7.
  const int frow = lane & 15;
  const int fk   = lane >> 4;                 // 0..3
  const int s0o  = ((fk ^ (lane & 7)) << 4);        // kk=0 slot byte
  const int s1o  = (((4 + fk) ^ (lane & 7)) << 4);  // kk=1 slot byte
  const int aRdC = (wm * 64 + frow) * 128;
  const int bRdC = (wn * 32 + frow) * 128;

  f32x4 acc[8][4];
  #pragma unroll
  for (int i = 0; i < 8; ++i)
    #pragma unroll
    for (int j = 0; j < 4; ++j) acc[i][j] = f32x4{0.f, 0.f, 0.f, 0.f};

  #define GATE(n) asm volatile("s_waitcnt vmcnt(" #n ")" ::: "memory")
  #define BARR()  asm volatile("s_barrier" ::: "memory")

  // Stage half-tile (2 global_load_lds per thread). kt = K-tile index.
  #define STAGE_A(g, buf, kt)                                                  \
    do {                                                                       \
      unsigned char* d_ = smem + (buf) * 32768 + (g) * 16384 + ldst;           \
      const u16* s_ = aRow + (size_t)((g) * 64) * Kt + (kt) * 64;              \
      async16(s_, d_);                                                         \
      async16(s_ + (size_t)128 * Kt, d_ + 8192);                               \
    } while (0)
  #define STAGE_B(p, buf, kt)                                                  \
    do {                                                                       \
      unsigned char* d_ = smem + 65536 + (buf) * 32768 + (p) * 16384 + ldst;   \
      const u16* s_ = bRow + (size_t)((p) * 32) * Kt + (kt) * 64;              \
      async16(s_, d_);                                                         \
      async16(s_ + (size_t)128 * Kt, d_ + 8192);                               \
    } while (0)

  // LDS fragment reads (compile-time indices -> registers).
  #define LD_A(dst, g, buf)                                                    \
    do {                                                                       \
      const unsigned char* b_ = smem + (buf) * 32768 + (g) * 16384 + aRdC;     \
      _Pragma("unroll")                                                        \
      for (int q_ = 0; q_ < 4; ++q_) {                                         \
        dst[q_][0] = *(const bf16x8*)(b_ + q_ * 2048 + s0o);                   \
        dst[q_][1] = *(const bf16x8*)(b_ + q_ * 2048 + s1o);                   \
      }                                                                        \
    } while (0)
  #define LD_B(dst, p, buf)                                                    \
    do {                                                                       \
      const unsigned char* b_ =                                                \
          smem + 65536 + (buf) * 32768 + (p) * 16384 + bRdC;                   \
      _Pragma("unroll")                                                        \
      for (int q_ = 0; q_ < 2; ++q_) {                                         \
        dst[q_][0] = *(const bf16x8*)(b_ + q_ * 2048 + s0o);                   \
        dst[q_][1] = *(const bf16x8*)(b_ + q_ * 2048 + s1o);                   \
      }                                                                        \
    } while (0)

  // MFMA cluster between barriers, kk OUTERMOST (dep distance 8). GN >= 0
  // inserts the tile's vmcnt gate BEFORE the closing barrier
  // (gate->barrier->read: cross-wave safe).
  #define MM_G(FG, FNP, A_, B_, GN)                                            \
    do {                                                                       \
      BARR();                                                                  \
      __builtin_amdgcn_s_setprio(1);                                           \
      _Pragma("unroll")                                                        \
      for (int kk_ = 0; kk_ < 2; ++kk_)                                        \
        _Pragma("unroll")                                                      \
        for (int fm_ = 0; fm_ < 4; ++fm_)                                      \
          _Pragma("unroll")                                                    \
          for (int fn_ = 0; fn_ < 2; ++fn_)                                    \
            acc[(FG) * 4 + fm_][(FNP) * 2 + fn_] =                             \
                __builtin_amdgcn_mfma_f32_16x16x32_bf16(                       \
                    A_[fm_][kk_], B_[fn_][kk_],                                \
                    acc[(FG) * 4 + fm_][(FNP) * 2 + fn_], 0, 0, 0);            \
      __builtin_amdgcn_s_setprio(0);                                           \
      if ((GN) == 6) { asm volatile("s_waitcnt vmcnt(6)" ::: "memory"); }      \
      else if ((GN) == 0) { asm volatile("s_waitcnt vmcnt(0)" ::: "memory"); } \
      BARR();                                                                  \
    } while (0)

  // One K-tile (4 phases). BUF is a literal; all LDS addrs fold to immediates.
  #define TILE(BUF, T, GN_LAST)                                                \
    do {                                                                       \
      LD_A(af, 0, BUF);                                                        \
      LD_B(b0, 0, BUF);                                                        \
      STAGE_A(1, BUF ^ 1, (T) + 1);                                            \
      MM_G(0, 0, af, b0, -1);                                                  \
      LD_B(b1, 1, BUF);                                                        \
      STAGE_A(0, BUF, (T) + 2);                                                \
      MM_G(0, 1, af, b1, -1);                                                  \
      LD_A(af, 1, BUF);                                                        \
      STAGE_B(0, BUF, (T) + 2);                                                \
      MM_G(1, 0, af, b0, -1);                                                  \
      STAGE_B(1, BUF, (T) + 2);                                                \
      MM_G(1, 1, af, b1, GN_LAST);                                             \
    } while (0)

  bf16x8 af[4][2], b0[2][2], b1[2][2];

  // Prologue: 7 half-tiles (14 loads): tile0 full set + tile1 minus A1.
  STAGE_A(0, 0, 0);   // A0(0)
  STAGE_B(0, 0, 0);   // B0(0)
  STAGE_B(1, 0, 0);   // B1(0)
  STAGE_A(1, 0, 0);   // A1(0)
  STAGE_A(0, 1, 1);   // A0(1)
  STAGE_B(0, 1, 1);   // B0(1)
  STAGE_B(1, 1, 1);   // B1(1)
  GATE(6);            // tile 0 fully landed (newest 6 = A0/B0/B1 of tile 1)
  BARR();             // ...visible to ALL waves' ds_reads

  // Steady loop: tiles 0..61 as 31 x (2 K-tiles). Stage calendar per tile:
  // ph0->A1(t+1), ph1->A0(t+2), ph2->B0(t+2), ph3->B1(t+2); GATE(6) at tile end.
  #pragma unroll 1
  for (int t0 = 0; t0 < NKT - 2; t0 += 2) {
    TILE(0, t0, 6);
    TILE(1, t0 + 1, 6);
  }

  // Peeled t = 62 (buf 0): only A1(63) stage remains; drain fully at tile end.
  {
    LD_A(af, 0, 0);
    LD_B(b0, 0, 0);
    STAGE_A(1, 1, 63);
    MM_G(0, 0, af, b0, -1);
    LD_B(b1, 1, 0);
    MM_G(0, 1, af, b1, -1);
    LD_A(af, 1, 0);
    MM_G(1, 0, af, b0, -1);
    MM_G(1, 1, af, b1, 0);   // GATE(0): tile 63 fully landed before barrier
  }
  // Peeled t = 63 (buf 1): no stages, no gates.
  {
    LD_A(af, 0, 1);
    LD_B(b0, 0, 1);
    MM_G(0, 0, af, b0, -1);
    LD_B(b1, 1, 1);
    MM_G(0, 1, af, b1, -1);
    LD_A(af, 1, 1);
    MM_G(1, 0, af, b0, -1);
    MM_G(1, 1, af, b1, -1);
  }

  #undef GATE
  #undef BARR
  #undef STAGE_A
  #undef STAGE_B
  #undef LD_A
  #undef LD_B
  #undef MM_G
  #undef TILE

  // Epilogue: C/D mapping col = lane&15, row = (lane>>4)*4 + reg (m89/m91).
  #pragma unroll
  for (int fm = 0; fm < 8; ++fm) {
    #pragma unroll
    for (int r2 = 0; r2 < 4; ++r2) {
      const size_t mrow = (size_t)(m0 + wm * 128 + fm * 16 + fk * 4 + r2) * Nt;
      #pragma unroll
      for (int fn = 0; fn < 4; ++fn) {
        Y[mrow + (size_t)(n0 + wn * 64 + fn * 16 + frow)] = acc[fm][fn][r2];
      }
    }
  }
}

// ---- fallback: fused single-buffer kernel (round-3 verified algebra) ----
__global__ __launch_bounds__(512) void gemm_fused(
    const float* __restrict__ Xf, const int* __restrict__ W,
    const float* __restrict__ S, float* __restrict__ Y) {
  constexpr int FBN = 128;
  constexpr int FNB = Nt / FBN;   // 86
  constexpr int FBK = 64;
  constexpr int FNKT = Kt / FBK;
  __shared__ __align__(16) unsigned char Alds[BM * FBK * 2];
  __shared__ __align__(16) unsigned char Blds[FBN * FBK * 2];

  const int tid = (int)threadIdx.x;
  const int lane = tid & 63;
  const int wid = tid >> 6;
  const int wm = wid >> 1;
  const int wn = wid & 1;

  const int bid = (int)blockIdx.x;
  const int fgrid = (Mt / BM) * FNB;
  const int wg = (bid & 7) * (fgrid / 8) + (bid >> 3);
  const int mb = wg / FNB;
  const int nb = wg - mb * FNB;
  const int m0 = mb * BM;
  const int n0 = nb * FBN;

  const int frow = lane & 15;
  const int fk = lane >> 4;
  const int fswz = (lane & 7) << 4;
  const unsigned char* aRd = Alds + (wm * 64 + frow) * 128;
  const unsigned char* bRd = Blds + (wn * 64 + frow) * 128;

  f32x4 acc[4][4];
  #pragma unroll
  for (int i = 0; i < 4; ++i)
    #pragma unroll
    for (int j = 0; j < 4; ++j) acc[i][j] = f32x4{0.f, 0.f, 0.f, 0.f};

  const int arow = tid >> 3, acol = tid & 7;
  const float* fA = Xf + (size_t)(m0 + arow) * Kt + acol * 8;
  unsigned char* fAD = Alds + arow * 128 + ((acol ^ (arow & 7)) << 4);
  const int nloc = tid >> 3, c4 = tid & 7;
  const int* fB0 = W + (size_t)(n0 + nloc) * KP + c4 * 4;
  const int* fB1 = fB0 + (size_t)64 * KP;
  const float* sp0 = S + (size_t)(n0 + nloc) * NG;
  const float* sp1 = sp0 + (size_t)64 * NG;
  unsigned char* fBD0 = Blds + nloc * 128 + ((c4 ^ (nloc & 7)) << 4);
  unsigned char* fBD1 = fBD0 + 64 * 128;

  #pragma unroll 1
  for (int kt = 0; kt < FNKT; ++kt) {
    const int k0 = kt * FBK;
    #pragma unroll
    for (int p = 0; p < 4; ++p) {
      float4 x0 = *(const float4*)(fA + (size_t)p * 64 * Kt + k0);
      float4 x1 = *(const float4*)(fA + (size_t)p * 64 * Kt + k0 + 4);
      u32x4 q;
      q[0] = pk2bf(x0.x, x0.y); q[1] = pk2bf(x0.z, x0.w);
      q[2] = pk2bf(x1.x, x1.y); q[3] = pk2bf(x1.z, x1.w);
      *(u32x4*)(fAD + p * 64 * 128) = q;
    }
    const int g = k0 >> 7;
    const float s0 = sp0[g], s1 = sp1[g];
    const float c0 = -8.f * s0, c1 = -8.f * s1;
    const int4 w0 = *(const int4*)(fB0 + (k0 >> 1));
    const int4 w1 = *(const int4*)(fB1 + (k0 >> 1));
    u32x4 q0, q1;
    q0[0] = dqpair((u32)w0.x, s0, c0); q0[1] = dqpair((u32)w0.y, s0, c0);
    q0[2] = dqpair((u32)w0.z, s0, c0); q0[3] = dqpair((u32)w0.w, s0, c0);
    q1[0] = dqpair((u32)w1.x, s1, c1); q1[1] = dqpair((u32)w1.y, s1, c1);
    q1[2] = dqpair((u32)w1.z, s1, c1); q1[3] = dqpair((u32)w1.w, s1, c1);
    *(u32x4*)fBD0 = q0;
    *(u32x4*)fBD1 = q1;

    __syncthreads();

    #pragma unroll
    for (int kk = 0; kk < 2; ++kk) {
      const int koff = (kk * 64 + fk * 16) ^ fswz;
      bf16x8 af[4], bfr[4];
      #pragma unroll
      for (int fm = 0; fm < 4; ++fm)
        af[fm] = *(const bf16x8*)(aRd + fm * 16 * 128 + koff);
      #pragma unroll
      for (int fn = 0; fn < 4; ++fn)
        bfr[fn] = *(const bf16x8*)(bRd + fn * 16 * 128 + koff);
      #pragma unroll
      for (int fm = 0; fm < 4; ++fm)
        #pragma unroll
        for (int fn = 0; fn < 4; ++fn)
          acc[fm][fn] = __builtin_amdgcn_mfma_f32_16x16x32_bf16(
              af[fm], bfr[fn], acc[fm][fn], 0, 0, 0);
    }
    __syncthreads();
  }

  #pragma unroll
  for (int fm = 0; fm < 4; ++fm) {
    #pragma unroll
    for (int r = 0; r < 4; ++r) {
      const size_t mrow = (size_t)(m0 + wm * 64 + fm * 16 + fk * 4 + r) * Nt;
      #pragma unroll
      for (int fn = 0; fn < 4; ++fn)
        Y[mrow + (size_t)(n0 + wn * 64 + fn * 16 + frow)] = acc[fm][fn][r];
    }
  }
}

}  // namespace

extern "C" void kernel_launch(void* const* d_in, const int* in_sizes, int n_in,
                              void* d_out, int out_size, void* d_ws, size_t ws_size,
                              hipStream_t stream) {
  (void)in_sizes; (void)n_in; (void)out_size;
  const float* X = (const float*)d_in[0];
  const int* W   = (const int*)d_in[1];
  const float* S = (const float*)d_in[2];
  float* Y       = (float*)d_out;

  const size_t xbytes = (size_t)Mt * Kt * 2;   // 64 MiB
  const size_t wbytes = (size_t)Nt * Kt * 2;   // 86 MiB

  if (ws_size >= xbytes + wbytes) {
    u16* Xb = (u16*)d_ws;
    u16* Wb = (u16*)((char*)d_ws + xbytes);
    cvt_x<<<dim3(2048), dim3(256), 0, stream>>>(X, (u32*)Xb);
    cvt_w<<<dim3(2048), dim3(256), 0, stream>>>(W, S, (u32*)Wb);
    gemm8p<<<dim3(GRID), dim3(THREADS), 0, stream>>>(Xb, Wb, Y);
  } else {
    gemm_fused<<<dim3((Mt / BM) * (Nt / 128)), dim3(512), 0, stream>>>(X, W, S, Y);
  }
}